// Round 9
// baseline (1693.467 us; speedup 1.0000x reference)
//
#include <hip/hip_runtime.h>

typedef unsigned short u16;
typedef unsigned int u32;
typedef __attribute__((ext_vector_type(8))) __bf16 bf16x8;
typedef __attribute__((ext_vector_type(4))) float f32x4;
typedef __attribute__((ext_vector_type(4))) u32 u32x4;

#define ASYNC16(g, l) __builtin_amdgcn_global_load_lds( \
    (const __attribute__((address_space(1))) unsigned int*)(g), \
    (__attribute__((address_space(3))) unsigned int*)(l), 16, 0, 0)

__device__ __forceinline__ u16 f2bf(float f){
  unsigned u = __float_as_uint(f);
  unsigned r = u + 0x7fffu + ((u >> 16) & 1u);
  return (u16)(r >> 16);
}

// ---------------- fp32 -> bf16 conversion ----------------
__global__ __launch_bounds__(256) void f2bf_kernel(const float* __restrict__ in,
                                                   u16* __restrict__ out, int n){
  int i = (blockIdx.x * 256 + threadIdx.x) * 8;
  if (i >= n) return;
  float4 a = *(const float4*)&in[i];
  float4 b = *(const float4*)&in[i + 4];
  u16 r[8] = {f2bf(a.x), f2bf(a.y), f2bf(a.z), f2bf(a.w),
              f2bf(b.x), f2bf(b.y), f2bf(b.z), f2bf(b.w)};
  *(uint4*)&out[i] = *(const uint4*)r;
}

// ---------------- ctx projections: ses_inf, h0 ----------------
__global__ __launch_bounds__(256) void ctx_kernel(const float* __restrict__ ctx,
    const float* __restrict__ Wses, const float* __restrict__ Ws2d,
    const float* __restrict__ bs2d, float* __restrict__ sesinf,
    float* __restrict__ h0f, u16* __restrict__ h0bf){
  int id = blockIdx.x * 4 + (threadIdx.x >> 6);
  int lane = threadIdx.x & 63;
  int n = id & 1023, b = (id >> 10) & 15, mat = id >> 14;
  const float* w = (mat ? Ws2d : Wses) + (size_t)n * 1024;
  const float* x = ctx + (size_t)b * 1024;
  float v = 0.f;
  #pragma unroll 4
  for (int k = lane; k < 1024; k += 64) v += x[k] * w[k];
  #pragma unroll
  for (int off = 32; off; off >>= 1) v += __shfl_down(v, off);
  if (lane == 0){
    if (mat == 0) sesinf[b * 1024 + n] = v;
    else {
      float t = tanhf(v + bs2d[n]);
      h0f[b * 1024 + n] = t;
      h0bf[b * 1024 + n] = f2bf(t);
    }
  }
}

// ---------------- embedding gather (bf16 rows) ----------------
__global__ void gather_kernel(const int* __restrict__ target,
                              const u16* __restrict__ embedBF, u16* __restrict__ embBF){
  int i = blockIdx.x;
  int t = target[i];
  int lane = threadIdx.x;
  *(uint4*)&embBF[(size_t)i * 512 + lane * 8] =
      *(const uint4*)&embedBF[(size_t)t * 512 + lane * 8];
}

// ---------------- maxout pairs -> bf16 ----------------
__global__ __launch_bounds__(256) void maxout_kernel(const float* __restrict__ total,
                                                     u16* __restrict__ mx){
  int idx = blockIdx.x * 256 + threadIdx.x; // 4096*512
  int r = idx >> 9, e = idx & 511;
  float a = total[(size_t)r * 1024 + 2 * e];
  float b = total[(size_t)r * 1024 + 2 * e + 1];
  mx[idx] = f2bf(fmaxf(a, b));
}

// ---------------- bf16 GEMM: C[M][N] = A[M][K] * B[N][K]^T (+epilogue) ----------------
// SWZ: bijective XCD-aware wgid remap (requires nwg % 8 == 0)
template<int EPI, int SWZ>
__global__ __launch_bounds__(256) void gemm_bt(
    const u16* __restrict__ A, const u16* __restrict__ B, float* __restrict__ C,
    int M, int N, int K,
    const float* __restrict__ bias, const float* __restrict__ add0,
    const float* __restrict__ add1)
{
  __shared__ u16 sA[2][128 * 32];
  __shared__ u16 sB[2][128 * 32];
  int bx = blockIdx.x, by = blockIdx.y;
  if (SWZ){
    int nwg = gridDim.x * gridDim.y;
    int wg = by * gridDim.x + bx;
    int q = nwg >> 3;
    int nw = (wg & 7) * q + (wg >> 3);
    bx = nw % gridDim.x; by = nw / gridDim.x;
  }
  const int n0 = bx * 128;
  const int m0 = by * 128;
  const int tid = threadIdx.x;
  const int lane = tid & 63;
  const int wid = tid >> 6;
  const int wm = (wid >> 1) * 64, wn = (wid & 1) * 64;
  const int l15 = lane & 15, kg = (lane >> 4) * 8;
  (void)M;

  f32x4 zero = {0.f, 0.f, 0.f, 0.f};
  f32x4 acc[4][4];
  #pragma unroll
  for (int m = 0; m < 4; m++)
    #pragma unroll
    for (int n = 0; n < 4; n++) acc[m][n] = zero;

  auto stage = [&](int buf, int kk){
    const u16* Ab = A + (size_t)m0 * K + kk;
    const u16* Bb = B + (size_t)n0 * K + kk;
    #pragma unroll
    for (int j = 0; j < 2; j++){
      int c = j * 256 + tid;
      ASYNC16(Ab + (size_t)(c >> 2) * K + (c & 3) * 8, &sA[buf][c * 8]);
    }
    #pragma unroll
    for (int j = 0; j < 2; j++){
      int c = j * 256 + tid;
      ASYNC16(Bb + (size_t)(c >> 2) * K + (c & 3) * 8, &sB[buf][c * 8]);
    }
  };

  stage(0, 0);
  int cur = 0;
  for (int kk = 0; kk < K; kk += 32){
    __syncthreads();
    if (kk + 32 < K) stage(cur ^ 1, kk + 32);
    bf16x8 af[4], bf_[4];
    #pragma unroll
    for (int m = 0; m < 4; m++)
      af[m] = *(const bf16x8*)&sA[cur][(wm + m * 16 + l15) * 32 + kg];
    #pragma unroll
    for (int n = 0; n < 4; n++)
      bf_[n] = *(const bf16x8*)&sB[cur][(wn + n * 16 + l15) * 32 + kg];
    #pragma unroll
    for (int m = 0; m < 4; m++)
      #pragma unroll
      for (int n = 0; n < 4; n++)
        acc[m][n] = __builtin_amdgcn_mfma_f32_16x16x32_bf16(af[m], bf_[n], acc[m][n], 0, 0, 0);
    cur ^= 1;
  }

  const int rb = m0 + wm + (lane >> 4) * 4;
  const int cb = n0 + wn + l15;
  #pragma unroll
  for (int m = 0; m < 4; m++){
    #pragma unroll
    for (int n = 0; n < 4; n++){
      #pragma unroll
      for (int i = 0; i < 4; i++){
        int row = rb + m * 16 + i;
        int col = cb + n * 16;
        float v = acc[m][n][i];
        if (EPI == 1) v += bias[col];
        if (EPI == 2) v += add0[(row >> 8) * N + col] + add1[(size_t)row * N + col];
        C[(size_t)row * N + col] = v;
      }
    }
  }
}

// ---------------- persistent GRU (flag-hinted, tag-validated dataflow) ----------------
// 64 WGs; WG g owns hidden cols [g*16, g*16+16). Wave w owns K-range
// [w*256, w*256+256) of gh (all 3 gates), h fragments reg-resident.
// LESSON (R7/R8 fail, R4/R6 pass): "flag visible => data visible" is NOT
// reliable when the consumer reads ~0 cycles after observing the flag --
// vmcnt(0) store-ack doesn't totally order many-CU data stores vs tid0's
// flag store at the coherence point. So: flags are a TIMING HINT only
// (thin polls, no fat speculative loads); correctness comes from R6's
// self-validating tags: xb[parity][batch][col] = (bf16(h)<<16) | step.
// Per chunk: flags ready -> 2x dwordx4 -> vmcnt(0)+sched_barrier (rule#18)
// -> tag check -> WAVE-UNIFORM accept (__all; MFMA is a wave op) -> perm
// repack -> MFMA. Rare lag => cheap per-chunk retry.
#define GRU_NWG 64
#define GRU_LDS 124672

__global__ __launch_bounds__(256) void gru_kernel(
    const u16* __restrict__ WhhBF, const float* __restrict__ bhh,
    const float* __restrict__ xproj, const float* __restrict__ h0f,
    const u16* __restrict__ h0bf, u16* __restrict__ hsBF,
    u32* __restrict__ xb, int* __restrict__ flags)
{
  extern __shared__ char smem[];
  u16*   Wl   = (u16*)smem;                        // [48][1032]
  float* gbuf = (float*)(smem + 99072);            // [2][3][256][4] f32
  float* hown = (float*)(smem + 99072 + 24576);    // [16][16] f32

  const int g = blockIdx.x;
  const int j0 = g * 16;
  const int tid = threadIdx.x;
  const int lane = tid & 63;
  const int wid = tid >> 6;
  const int bb = tid >> 4, jj = tid & 15;   // gates-phase mapping
  const int l15 = lane & 15, kh = lane >> 4;
  const int Koff = wid * 256;

  // one-time: W_hh slice -> LDS (rows {j, H+j, 2H+j})
  for (int c = tid; c < 48 * 128; c += 256){
    int r = c >> 7, cg = (c & 127) * 8;
    int gate = r >> 4, n = r & 15;
    *(uint4*)&Wl[r * 1032 + cg] =
        *(const uint4*)&WhhBF[(size_t)(gate * 1024 + j0 + n) * 1024 + cg];
  }
  hown[bb * 16 + jj] = h0f[bb * 1024 + j0 + jj];
  const float bh0 = bhh[j0 + jj];
  const float bh1 = bhh[1024 + j0 + jj];
  const float bh2 = bhh[2048 + j0 + jj];
  __syncthreads();

  const f32x4 zero = {0.f, 0.f, 0.f, 0.f};

  for (int s = 0; s < 256; ++s){
    // xproj loads issued at step top: consumed only in gates (full-step cover)
    const float* xp = xproj + ((size_t)(bb << 8) + s) * 3072;
    float xr = xp[j0 + jj], xz = xp[1024 + j0 + jj], xn = xp[2048 + j0 + jj];

    f32x4 acc0 = zero, acc1 = zero, acc2 = zero;

    #define DO_CHUNK(a8, c) { \
      const int ko = Koff + (c) * 32 + kh * 8; \
      bf16x8 w0 = *(const bf16x8*)&Wl[l15 * 1032 + ko]; \
      bf16x8 w1 = *(const bf16x8*)&Wl[(16 + l15) * 1032 + ko]; \
      bf16x8 w2 = *(const bf16x8*)&Wl[(32 + l15) * 1032 + ko]; \
      acc0 = __builtin_amdgcn_mfma_f32_16x16x32_bf16((a8), w0, acc0, 0, 0, 0); \
      acc1 = __builtin_amdgcn_mfma_f32_16x16x32_bf16((a8), w1, acc1, 0, 0, 0); \
      acc2 = __builtin_amdgcn_mfma_f32_16x16x32_bf16((a8), w2, acc2, 0, 0, 0); }

    if (s == 0){
      #pragma unroll
      for (int c = 0; c < 8; c++){
        bf16x8 a = *(const bf16x8*)&h0bf[l15 * 1024 + Koff + c * 32 + kh * 8];
        DO_CHUNK(a, c);
      }
    } else {
      // tagged dwords: index = parity<<14 | batch*1024 + col
      const u32* base = xb + ((u32)(s & 1) << 14) + l15 * 1024 + Koff + kh * 8;
      u32 pend = 0xFFu;
      u32x4 ta[8], tb[8];
      while (pend){
        int myf = 0;
        if (lane < 16)
          myf = __hip_atomic_load(&flags[(wid * 16 + lane) * 32],
                                  __ATOMIC_RELAXED, __HIP_MEMORY_SCOPE_AGENT);
        u32 bal = (u32)(__ballot(myf >= s) & 0xFFFFull);
        u32 newm = 0;
        #pragma unroll
        for (int c = 0; c < 8; c++)
          if (((bal >> (2 * c)) & 3u) == 3u) newm |= (1u << c);
        newm &= pend;
        if (newm){
          #pragma unroll
          for (int c = 0; c < 8; c++)
            if (newm & (1u << c)){
              asm volatile("global_load_dwordx4 %0, %1, off sc1"
                           : "=v"(ta[c]) : "v"(base + c * 32) : "memory");
              asm volatile("global_load_dwordx4 %0, %1, off sc1"
                           : "=v"(tb[c]) : "v"(base + c * 32 + 4) : "memory");
            }
          asm volatile("s_waitcnt vmcnt(0)" ::: "memory");
          __builtin_amdgcn_sched_barrier(0);   // rule#18: no hoist past waitcnt
          #pragma unroll
          for (int c = 0; c < 8; c++)
            if (newm & (1u << c)){
              u32x4 a = ta[c], b = tb[c];
              u32 m = ((a[0] ^ (u32)s) | (a[1] ^ (u32)s) |
                       (a[2] ^ (u32)s) | (a[3] ^ (u32)s) |
                       (b[0] ^ (u32)s) | (b[1] ^ (u32)s) |
                       (b[2] ^ (u32)s) | (b[3] ^ (u32)s)) & 0xFFFFu;
              if (__all(m == 0)){   // wave-uniform accept (MFMA is a wave op)
                u32 dd[4];
                dd[0] = __builtin_amdgcn_perm(a[1], a[0], 0x07060302u);
                dd[1] = __builtin_amdgcn_perm(a[3], a[2], 0x07060302u);
                dd[2] = __builtin_amdgcn_perm(b[1], b[0], 0x07060302u);
                dd[3] = __builtin_amdgcn_perm(b[3], b[2], 0x07060302u);
                bf16x8 a8 = *(const bf16x8*)dd;
                DO_CHUNK(a8, c);
                pend &= ~(1u << c);
              }
            }
        } else {
          __builtin_amdgcn_s_sleep(1);
        }
      }
    }
    #undef DO_CHUNK

    // partial write: gbuf[parity][gate][batch*16+col][wave]
    float* gb = gbuf + (s & 1) * 3072;
    #pragma unroll
    for (int i = 0; i < 4; i++){
      int rc = (kh * 4 + i) * 16 + l15;
      gb[(0 * 256 + rc) * 4 + wid] = acc0[i];
      gb[(1 * 256 + rc) * 4 + wid] = acc1[i];
      gb[(2 * 256 + rc) * 4 + wid] = acc2[i];
    }
    __syncthreads();

    // gates (all 256 threads, one (batch,col) each) + tagged publish
    {
      const float* gq = gbuf + (s & 1) * 3072;
      f32x4 p0 = *(const f32x4*)&gq[(0 * 256 + tid) * 4];
      f32x4 p1 = *(const f32x4*)&gq[(1 * 256 + tid) * 4];
      f32x4 p2 = *(const f32x4*)&gq[(2 * 256 + tid) * 4];
      float hr = p0[0] + p0[1] + p0[2] + p0[3] + bh0;
      float hz = p1[0] + p1[1] + p1[2] + p1[3] + bh1;
      float hn = p2[0] + p2[1] + p2[2] + p2[3] + bh2;
      float r = 1.f / (1.f + __expf(-(xr + hr)));
      float z = 1.f / (1.f + __expf(-(xz + hz)));
      float nn = tanhf(xn + r * hn);
      float hnew = (1.f - z) * nn + z * hown[bb * 16 + jj];
      hown[bb * 16 + jj] = hnew;
      u16 hv = f2bf(hnew);
      hsBF[((size_t)(bb << 8) + s) * 1024 + j0 + jj] = hv;  // plain (read post-kernel)
      if (s < 255){
        u32 pack = ((u32)hv << 16) | (u32)(s + 1);
        __hip_atomic_store(&xb[((u32)(((s + 1) & 1)) << 14) + bb * 1024 + j0 + jj],
                           pack, __ATOMIC_RELAXED, __HIP_MEMORY_SCOPE_AGENT);
        asm volatile("s_waitcnt vmcnt(0)" ::: "memory");
        __syncthreads();
        if (tid == 0)
          __hip_atomic_store(&flags[g * 32], s + 1, __ATOMIC_RELAXED,
                             __HIP_MEMORY_SCOPE_AGENT);
      }
    }
  }
}

extern "C" void kernel_launch(void* const* d_in, const int* in_sizes, int n_in,
                              void* d_out, int out_size, void* d_ws, size_t ws_size,
                              hipStream_t stream)
{
  const float* ctx    = (const float*)d_in[0];
  const int*   target = (const int*)d_in[1];
  const float* embed  = (const float*)d_in[2];
  const float* Ws2d   = (const float*)d_in[3];
  const float* bs2d   = (const float*)d_in[4];
  const float* Wdec   = (const float*)d_in[5];
  const float* Wses   = (const float*)d_in[6];
  const float* Wemb   = (const float*)d_in[7];
  const float* bemb   = (const float*)d_in[8];
  const float* Wih    = (const float*)d_in[9];
  const float* Whh    = (const float*)d_in[10];
  const float* bih    = (const float*)d_in[11];
  const float* bhh    = (const float*)d_in[12];
  float* out = (float*)d_out;

  char* ws = (char*)d_ws;
  size_t off = 0;
  auto alloc = [&](size_t bytes)->char*{
    char* p = ws + off; off += (bytes + 255) & ~(size_t)255; return p;
  };
  u16*   embedBF = (u16*)alloc(32000ull * 512 * 2);
  u16*   WihBF   = (u16*)alloc(3072ull * 512 * 2);
  u16*   WembBF  = (u16*)alloc(1024ull * 512 * 2);
  u16*   WdecBF  = (u16*)alloc(1024ull * 1024 * 2);
  u16*   WhhBF   = (u16*)alloc(3072ull * 1024 * 2);
  u16*   embBF   = (u16*)alloc(4096ull * 512 * 2);
  float* xproj   = (float*)alloc(4096ull * 3072 * 4);
  float* embinf  = (float*)alloc(4096ull * 1024 * 4);
  float* sesinf  = (float*)alloc(16ull * 1024 * 4);
  float* h0f     = (float*)alloc(16ull * 1024 * 4);
  u16*   h0bf    = (u16*)alloc(16ull * 1024 * 2);
  u16*   hsBF    = (u16*)alloc(4096ull * 1024 * 2);
  float* total   = (float*)alloc(4096ull * 1024 * 4);
  u16*   mxBF    = (u16*)alloc(4096ull * 512 * 2);
  u32*   xbuf    = (u32*)alloc(2ull * 16 * 1024 * 4);   // [2][16][1024] tagged dwords
  int*   flags   = (int*)alloc(16384);
  (void)ws_size; (void)in_sizes; (void)n_in; (void)out_size;

  hipFuncSetAttribute((const void*)gru_kernel,
                      hipFuncAttributeMaxDynamicSharedMemorySize, GRU_LDS);
  // xbuf and flags are contiguous (both 256-aligned sizes): one async clear.
  hipMemsetAsync(xbuf, 0, 2ull * 16 * 1024 * 4 + 16384, stream);

  auto conv = [&](const float* in, u16* o, size_t n){
    f2bf_kernel<<<dim3((unsigned)((n / 8 + 255) / 256)), 256, 0, stream>>>(in, o, (int)n);
  };
  conv(embed, embedBF, 32000ull * 512);
  conv(Wih,   WihBF,   3072ull * 512);
  conv(Wemb,  WembBF,  1024ull * 512);
  conv(Wdec,  WdecBF,  1024ull * 1024);
  conv(Whh,   WhhBF,   3072ull * 1024);

  ctx_kernel<<<8192, 256, 0, stream>>>(ctx, Wses, Ws2d, bs2d, sesinf, h0f, h0bf);
  gather_kernel<<<4096, 64, 0, stream>>>(target, embedBF, embBF);

  // x_proj = emb @ W_ih^T + b_ih ; emb_inf = emb @ W_emb^T + b_emb
  gemm_bt<1,0><<<dim3(3072 / 128, 4096 / 128), 256, 0, stream>>>(
      embBF, WihBF, xproj, 4096, 3072, 512, bih, nullptr, nullptr);
  gemm_bt<1,0><<<dim3(1024 / 128, 4096 / 128), 256, 0, stream>>>(
      embBF, WembBF, embinf, 4096, 1024, 512, bemb, nullptr, nullptr);

  gru_kernel<<<GRU_NWG, 256, GRU_LDS, stream>>>(WhhBF, bhh, xproj, h0f, h0bf,
                                                hsBF, xbuf, flags);

  // total = hs @ W_dec^T + ses_inf[b] + emb_inf
  gemm_bt<2,0><<<dim3(1024 / 128, 4096 / 128), 256, 0, stream>>>(
      hsBF, WdecBF, total, 4096, 1024, 1024, nullptr, sesinf, embinf);
  maxout_kernel<<<8192, 256, 0, stream>>>(total, mxBF);

  // logits = mx @ embed^T  (XCD-swizzled: 8000 WGs % 8 == 0)
  gemm_bt<0,1><<<dim3(32000 / 128, 4096 / 128), 256, 0, stream>>>(
      mxBF, embedBF, out, 4096, 32000, 512, nullptr, nullptr, nullptr);
}

// Round 10
// 1323.350 us; speedup vs baseline: 1.2797x; 1.2797x over previous
//
#include <hip/hip_runtime.h>

typedef unsigned short u16;
typedef unsigned int u32;
typedef __attribute__((ext_vector_type(8))) __bf16 bf16x8;
typedef __attribute__((ext_vector_type(4))) float f32x4;
typedef __attribute__((ext_vector_type(4))) u32 u32x4;

#define ASYNC16(g, l) __builtin_amdgcn_global_load_lds( \
    (const __attribute__((address_space(1))) unsigned int*)(g), \
    (__attribute__((address_space(3))) unsigned int*)(l), 16, 0, 0)

__device__ __forceinline__ u16 f2bf(float f){
  unsigned u = __float_as_uint(f);
  unsigned r = u + 0x7fffu + ((u >> 16) & 1u);
  return (u16)(r >> 16);
}

// ---------------- fp32 -> bf16 conversion ----------------
__global__ __launch_bounds__(256) void f2bf_kernel(const float* __restrict__ in,
                                                   u16* __restrict__ out, int n){
  int i = (blockIdx.x * 256 + threadIdx.x) * 8;
  if (i >= n) return;
  float4 a = *(const float4*)&in[i];
  float4 b = *(const float4*)&in[i + 4];
  u16 r[8] = {f2bf(a.x), f2bf(a.y), f2bf(a.z), f2bf(a.w),
              f2bf(b.x), f2bf(b.y), f2bf(b.z), f2bf(b.w)};
  *(uint4*)&out[i] = *(const uint4*)r;
}

// ---------------- ctx projections: ses_inf, h0 ----------------
__global__ __launch_bounds__(256) void ctx_kernel(const float* __restrict__ ctx,
    const float* __restrict__ Wses, const float* __restrict__ Ws2d,
    const float* __restrict__ bs2d, float* __restrict__ sesinf,
    float* __restrict__ h0f, u16* __restrict__ h0bf){
  int id = blockIdx.x * 4 + (threadIdx.x >> 6);
  int lane = threadIdx.x & 63;
  int n = id & 1023, b = (id >> 10) & 15, mat = id >> 14;
  const float* w = (mat ? Ws2d : Wses) + (size_t)n * 1024;
  const float* x = ctx + (size_t)b * 1024;
  float v = 0.f;
  #pragma unroll 4
  for (int k = lane; k < 1024; k += 64) v += x[k] * w[k];
  #pragma unroll
  for (int off = 32; off; off >>= 1) v += __shfl_down(v, off);
  if (lane == 0){
    if (mat == 0) sesinf[b * 1024 + n] = v;
    else {
      float t = tanhf(v + bs2d[n]);
      h0f[b * 1024 + n] = t;
      h0bf[b * 1024 + n] = f2bf(t);
    }
  }
}

// ---------------- embedding gather (bf16 rows) ----------------
__global__ void gather_kernel(const int* __restrict__ target,
                              const u16* __restrict__ embedBF, u16* __restrict__ embBF){
  int i = blockIdx.x;
  int t = target[i];
  int lane = threadIdx.x;
  *(uint4*)&embBF[(size_t)i * 512 + lane * 8] =
      *(const uint4*)&embedBF[(size_t)t * 512 + lane * 8];
}

// ---------------- bf16 GEMM: C[M][N] = A[M][K] * B[N][K]^T (+epilogue) ----------------
// SWZ: bijective XCD-aware wgid remap (requires nwg % 8 == 0)
// EPI: 0=none, 1=+bias[col], 2=+add0+add1 -> C, 3=+add0+add1 -> pairwise-max -> bf16 mxout
template<int EPI, int SWZ>
__global__ __launch_bounds__(256) void gemm_bt(
    const u16* __restrict__ A, const u16* __restrict__ B, float* __restrict__ C,
    int M, int N, int K,
    const float* __restrict__ bias, const float* __restrict__ add0,
    const float* __restrict__ add1, u16* __restrict__ mxout)
{
  __shared__ u16 sA[2][128 * 32];
  __shared__ u16 sB[2][128 * 32];
  int bx = blockIdx.x, by = blockIdx.y;
  if (SWZ){
    int nwg = gridDim.x * gridDim.y;
    int wg = by * gridDim.x + bx;
    int q = nwg >> 3;
    int nw = (wg & 7) * q + (wg >> 3);
    bx = nw % gridDim.x; by = nw / gridDim.x;
  }
  const int n0 = bx * 128;
  const int m0 = by * 128;
  const int tid = threadIdx.x;
  const int lane = tid & 63;
  const int wid = tid >> 6;
  const int wm = (wid >> 1) * 64, wn = (wid & 1) * 64;
  const int l15 = lane & 15, kg = (lane >> 4) * 8;
  (void)M;

  f32x4 zero = {0.f, 0.f, 0.f, 0.f};
  f32x4 acc[4][4];
  #pragma unroll
  for (int m = 0; m < 4; m++)
    #pragma unroll
    for (int n = 0; n < 4; n++) acc[m][n] = zero;

  auto stage = [&](int buf, int kk){
    const u16* Ab = A + (size_t)m0 * K + kk;
    const u16* Bb = B + (size_t)n0 * K + kk;
    #pragma unroll
    for (int j = 0; j < 2; j++){
      int c = j * 256 + tid;
      ASYNC16(Ab + (size_t)(c >> 2) * K + (c & 3) * 8, &sA[buf][c * 8]);
    }
    #pragma unroll
    for (int j = 0; j < 2; j++){
      int c = j * 256 + tid;
      ASYNC16(Bb + (size_t)(c >> 2) * K + (c & 3) * 8, &sB[buf][c * 8]);
    }
  };

  stage(0, 0);
  int cur = 0;
  for (int kk = 0; kk < K; kk += 32){
    __syncthreads();
    if (kk + 32 < K) stage(cur ^ 1, kk + 32);
    bf16x8 af[4], bf_[4];
    #pragma unroll
    for (int m = 0; m < 4; m++)
      af[m] = *(const bf16x8*)&sA[cur][(wm + m * 16 + l15) * 32 + kg];
    #pragma unroll
    for (int n = 0; n < 4; n++)
      bf_[n] = *(const bf16x8*)&sB[cur][(wn + n * 16 + l15) * 32 + kg];
    #pragma unroll
    for (int m = 0; m < 4; m++)
      #pragma unroll
      for (int n = 0; n < 4; n++)
        acc[m][n] = __builtin_amdgcn_mfma_f32_16x16x32_bf16(af[m], bf_[n], acc[m][n], 0, 0, 0);
    cur ^= 1;
  }

  const int rb = m0 + wm + (lane >> 4) * 4;
  const int cb = n0 + wn + l15;
  #pragma unroll
  for (int m = 0; m < 4; m++){
    #pragma unroll
    for (int n = 0; n < 4; n++){
      #pragma unroll
      for (int i = 0; i < 4; i++){
        int row = rb + m * 16 + i;
        int col = cb + n * 16;
        float v = acc[m][n][i];
        if (EPI == 1) v += bias[col];
        if (EPI == 2 || EPI == 3)
          v += add0[(row >> 8) * N + col] + add1[(size_t)row * N + col];
        if (EPI == 3){
          // pairwise maxout: col pairs (2e,2e+1) live in adjacent lanes
          float w = __shfl_xor(v, 1);
          if ((l15 & 1) == 0)
            mxout[(size_t)row * (N >> 1) + (col >> 1)] = f2bf(fmaxf(v, w));
        } else {
          C[(size_t)row * N + col] = v;
        }
      }
    }
  }
}

// ---------------- persistent GRU (R4 structure, verbatim — best measured) ----------------
// 64 WGs; WG g owns hidden cols [g*16, g*16+16).
// No cache-invalidating fences in the loop. Cross-WG data moves only via
// explicitly-coherent accesses: h_new stored with sc1 (write-through to
// coherence point), h re-staged with inline-asm global_load_dwordx4 sc1
// (bypass L1/L2). L2 stays warm for read-only data (xproj, W, h0bf).
// Barrier: drain(vmcnt0) -> flag[g] store (own 128B line) -> every WG's
// wave0 polls the 64 flag lines (lane l -> line l).
#define GRU_NWG 64
#define GRU_LDS 136192

__global__ __launch_bounds__(256) void gru_kernel(
    const u16* __restrict__ WhhBF, const float* __restrict__ bhh,
    const float* __restrict__ xproj, const float* __restrict__ h0f,
    const u16* __restrict__ h0bf, u16* __restrict__ hsBF, int* flags)
{
  extern __shared__ char smem[];
  u16*  Wl   = (u16*)smem;                 // [48][1032]
  u16*  hb   = Wl + 48 * 1032;             // [16][1032]
  float* gbuf = (float*)(smem + 132096);   // [3][16][16]
  float* hown = gbuf + 3 * 256;            // [16][16]

  const int g = blockIdx.x;
  const int j0 = g * 16;
  const int tid = threadIdx.x;
  const int lane = tid & 63;
  const int wid = tid >> 6;
  const int bb = tid >> 4, jj = tid & 15;   // gates-phase mapping

  // one-time: W_hh slice -> LDS (rows {j, H+j, 2H+j})
  for (int c = tid; c < 48 * 128; c += 256){
    int r = c >> 7, cg = (c & 127) * 8;
    int gate = r >> 4, n = r & 15;
    *(uint4*)&Wl[r * 1032 + cg] =
        *(const uint4*)&WhhBF[(size_t)(gate * 1024 + j0 + n) * 1024 + cg];
  }
  hown[bb * 16 + jj] = h0f[bb * 1024 + j0 + jj];
  const float bh0 = bhh[j0 + jj];
  const float bh1 = bhh[1024 + j0 + jj];
  const float bh2 = bhh[2048 + j0 + jj];
  u32* hs32 = (u32*)hsBF;
  __syncthreads();

  for (int s = 0; s < 256; ++s){
    // ---- stage h_{s-1} into LDS ----
    if (s == 0){
      #pragma unroll
      for (int k = 0; k < 8; k++){
        int c = tid + k * 256;
        int b = c >> 7, cg = (c & 127) * 8;
        *(uint4*)&hb[b * 1032 + cg] = *(const uint4*)&h0bf[b * 1024 + cg];
      }
    } else {
      u32x4 r[8];
      #pragma unroll
      for (int k = 0; k < 8; k++){
        int c = tid + k * 256;
        int b = c >> 7, cg = (c & 127) * 8;
        const u16* src = &hsBF[(size_t)((b << 8) + s - 1) * 1024 + cg];
        asm volatile("global_load_dwordx4 %0, %1, off sc1"
                     : "=v"(r[k]) : "v"(src) : "memory");
      }
      asm volatile("s_waitcnt vmcnt(0)" ::: "memory");
      __builtin_amdgcn_sched_barrier(0);   // rule#18 hygiene
      #pragma unroll
      for (int k = 0; k < 8; k++){
        int c = tid + k * 256;
        int b = c >> 7, cg = (c & 127) * 8;
        *(u32x4*)&hb[b * 1032 + cg] = r[k];
      }
    }

    // prefetch this step's x_proj scalars (consumed after MFMA phase)
    const float* xp = xproj + ((size_t)(bb << 8) + s) * 3072;
    float xr = xp[j0 + jj], xz = xp[1024 + j0 + jj], xn = xp[2048 + j0 + jj];
    __syncthreads();

    // gh slice: waves 0..2 = gates r,z,n ; M=16(batch) N=16(cols) K=1024
    if (wid < 3){
      f32x4 acc0 = {0.f, 0.f, 0.f, 0.f};
      f32x4 acc1 = {0.f, 0.f, 0.f, 0.f};
      const int l15 = lane & 15, kg = (lane >> 4) * 8;
      const u16* wrow = &Wl[(wid * 16 + l15) * 1032];
      const u16* hrow = &hb[l15 * 1032];
      #pragma unroll 8
      for (int kk = 0; kk < 1024; kk += 64){
        bf16x8 a0 = *(const bf16x8*)&hrow[kk + kg];
        bf16x8 w0 = *(const bf16x8*)&wrow[kk + kg];
        acc0 = __builtin_amdgcn_mfma_f32_16x16x32_bf16(a0, w0, acc0, 0, 0, 0);
        bf16x8 a1 = *(const bf16x8*)&hrow[kk + 32 + kg];
        bf16x8 w1 = *(const bf16x8*)&wrow[kk + 32 + kg];
        acc1 = __builtin_amdgcn_mfma_f32_16x16x32_bf16(a1, w1, acc1, 0, 0, 0);
      }
      #pragma unroll
      for (int i = 0; i < 4; ++i)
        gbuf[wid * 256 + ((lane >> 4) * 4 + i) * 16 + l15] = acc0[i] + acc1[i];
    }
    __syncthreads();

    // gates (fp32); write h_new as write-through agent-scope dword stores
    {
      float hr = gbuf[0 * 256 + bb * 16 + jj] + bh0;
      float hz = gbuf[1 * 256 + bb * 16 + jj] + bh1;
      float hn = gbuf[2 * 256 + bb * 16 + jj] + bh2;
      float r = 1.f / (1.f + __expf(-(xr + hr)));
      float z = 1.f / (1.f + __expf(-(xz + hz)));
      float nn = tanhf(xn + r * hn);
      float hnew = (1.f - z) * nn + z * hown[bb * 16 + jj];
      hown[bb * 16 + jj] = hnew;
      float hnext = __shfl_down(hnew, 1);
      if ((jj & 1) == 0){
        u32 pack = (u32)f2bf(hnew) | ((u32)f2bf(hnext) << 16);
        size_t e = (size_t)((bb << 8) + s) * 1024 + j0 + jj;
        __hip_atomic_store(&hs32[e >> 1], pack, __ATOMIC_RELAXED,
                           __HIP_MEMORY_SCOPE_AGENT);
      }
    }

    if (s < 255){
      asm volatile("s_waitcnt vmcnt(0)" ::: "memory");
      __syncthreads();
      if (tid == 0)
        __hip_atomic_store(&flags[g * 32], s + 1, __ATOMIC_RELAXED,
                           __HIP_MEMORY_SCOPE_AGENT);
      if (wid == 0){
        while (__hip_atomic_load(&flags[lane * 32], __ATOMIC_RELAXED,
                                 __HIP_MEMORY_SCOPE_AGENT) <= s)
          __builtin_amdgcn_s_sleep(1);
      }
      __syncthreads();
    }
  }
}

extern "C" void kernel_launch(void* const* d_in, const int* in_sizes, int n_in,
                              void* d_out, int out_size, void* d_ws, size_t ws_size,
                              hipStream_t stream)
{
  const float* ctx    = (const float*)d_in[0];
  const int*   target = (const int*)d_in[1];
  const float* embed  = (const float*)d_in[2];
  const float* Ws2d   = (const float*)d_in[3];
  const float* bs2d   = (const float*)d_in[4];
  const float* Wdec   = (const float*)d_in[5];
  const float* Wses   = (const float*)d_in[6];
  const float* Wemb   = (const float*)d_in[7];
  const float* bemb   = (const float*)d_in[8];
  const float* Wih    = (const float*)d_in[9];
  const float* Whh    = (const float*)d_in[10];
  const float* bih    = (const float*)d_in[11];
  const float* bhh    = (const float*)d_in[12];
  float* out = (float*)d_out;

  char* ws = (char*)d_ws;
  size_t off = 0;
  auto alloc = [&](size_t bytes)->char*{
    char* p = ws + off; off += (bytes + 255) & ~(size_t)255; return p;
  };
  u16*   embedBF = (u16*)alloc(32000ull * 512 * 2);
  u16*   WihBF   = (u16*)alloc(3072ull * 512 * 2);
  u16*   WembBF  = (u16*)alloc(1024ull * 512 * 2);
  u16*   WdecBF  = (u16*)alloc(1024ull * 1024 * 2);
  u16*   WhhBF   = (u16*)alloc(3072ull * 1024 * 2);
  u16*   embBF   = (u16*)alloc(4096ull * 512 * 2);
  float* xproj   = (float*)alloc(4096ull * 3072 * 4);
  float* embinf  = (float*)alloc(4096ull * 1024 * 4);
  float* sesinf  = (float*)alloc(16ull * 1024 * 4);
  float* h0f     = (float*)alloc(16ull * 1024 * 4);
  u16*   h0bf    = (u16*)alloc(16ull * 1024 * 2);
  u16*   hsBF    = (u16*)alloc(4096ull * 1024 * 2);
  u16*   mxBF    = (u16*)alloc(4096ull * 512 * 2);
  int*   flags   = (int*)alloc(16384);
  (void)ws_size; (void)in_sizes; (void)n_in; (void)out_size;

  hipFuncSetAttribute((const void*)gru_kernel,
                      hipFuncAttributeMaxDynamicSharedMemorySize, GRU_LDS);
  hipMemsetAsync(flags, 0, 16384, stream);

  auto conv = [&](const float* in, u16* o, size_t n){
    f2bf_kernel<<<dim3((unsigned)((n / 8 + 255) / 256)), 256, 0, stream>>>(in, o, (int)n);
  };
  conv(embed, embedBF, 32000ull * 512);
  conv(Wih,   WihBF,   3072ull * 512);
  conv(Wemb,  WembBF,  1024ull * 512);
  conv(Wdec,  WdecBF,  1024ull * 1024);
  conv(Whh,   WhhBF,   3072ull * 1024);

  ctx_kernel<<<8192, 256, 0, stream>>>(ctx, Wses, Ws2d, bs2d, sesinf, h0f, h0bf);
  gather_kernel<<<4096, 64, 0, stream>>>(target, embedBF, embBF);

  // x_proj = emb @ W_ih^T + b_ih ; emb_inf = emb @ W_emb^T + b_emb
  gemm_bt<1,0><<<dim3(3072 / 128, 4096 / 128), 256, 0, stream>>>(
      embBF, WihBF, xproj, 4096, 3072, 512, bih, nullptr, nullptr, nullptr);
  gemm_bt<1,0><<<dim3(1024 / 128, 4096 / 128), 256, 0, stream>>>(
      embBF, WembBF, embinf, 4096, 1024, 512, bemb, nullptr, nullptr, nullptr);

  gru_kernel<<<GRU_NWG, 256, GRU_LDS, stream>>>(WhhBF, bhh, xproj, h0f, h0bf, hsBF, flags);

  // total = hs @ W_dec^T + ses_inf[b] + emb_inf ; fused pairwise-maxout -> mxBF
  gemm_bt<3,0><<<dim3(1024 / 128, 4096 / 128), 256, 0, stream>>>(
      hsBF, WdecBF, nullptr, 4096, 1024, 1024, nullptr, sesinf, embinf, mxBF);

  // logits = mx @ embed^T  (XCD-swizzled: 8000 WGs % 8 == 0)
  gemm_bt<0,1><<<dim3(32000 / 128, 4096 / 128), 256, 0, stream>>>(
      mxBF, embedBF, out, 4096, 32000, 512, nullptr, nullptr, nullptr, nullptr);
}